// Round 7
// baseline (240.439 us; speedup 1.0000x reference)
//
#include <hip/hip_runtime.h>
#include <hip/hip_bf16.h>

// MHA layer. B=4, S=2048, HID=512, H=8, HD=64. fp32 in/out, bf16 MFMA inside.
// R7: attn softmax VALU cuts:
//  - Wq/bq pre-scaled by 0.125*log2(e) => scores are exp2-ready; p=exp2f(s+mb)
//    is a single v_exp_f32 (ISA: D=2^S0). No per-element mul/fma.
//  - l computed by MFMA with ones-B-fragment: row sums land in C-layout
//    aligned with o rows; kills ssum adds + epilogue shuffles.
//  - Pls padding 72->88 (R3-measured: 1.0M vs 3.1M conflict cycles).
// Rest unchanged from R6 (register-prefetch pipelines everywhere).

typedef __bf16 v8bf __attribute__((ext_vector_type(8)));
typedef __bf16 v4bf __attribute__((ext_vector_type(4)));
typedef float  v4f  __attribute__((ext_vector_type(4)));

#define MFMA16(a, b, c) __builtin_amdgcn_mfma_f32_16x16x32_bf16((a), (b), (c), 0, 0, 0)

// 0.125 * log2(e): folded into Wq/bq so softmax uses exp2 directly.
#define QSCALE 0.1803368801111f

__device__ inline v8bf cvt8(const float* __restrict__ p) {
    const v4f f0 = *(const v4f*)p;
    const v4f f1 = *(const v4f*)(p + 4);
    v8bf r;
    r[0] = (__bf16)f0[0]; r[1] = (__bf16)f0[1]; r[2] = (__bf16)f0[2]; r[3] = (__bf16)f0[3];
    r[4] = (__bf16)f1[0]; r[5] = (__bf16)f1[1]; r[6] = (__bf16)f1[2]; r[7] = (__bf16)f1[3];
    return r;
}

// ---------------------------------------------------------------------------
// K0: convert Wq,Wk,Wv,Wo (each 512x512 fp32) -> bf16, concatenated.
// Wq additionally scaled by QSCALE (softmax exp2 folding).
// ---------------------------------------------------------------------------
__global__ __launch_bounds__(256) void cvt_w(
    const float* __restrict__ Wq, const float* __restrict__ Wk,
    const float* __restrict__ Wv, const float* __restrict__ Wo,
    __bf16* __restrict__ out)
{
    const int idx = (blockIdx.x * 256 + threadIdx.x) * 4;
    const int w = idx >> 18, off = idx & 262143;
    const float* src = (w == 0) ? Wq : (w == 1) ? Wk : (w == 2) ? Wv : Wo;
    const float sc = (w == 0) ? QSCALE : 1.0f;
    const v4f x = *(const v4f*)(src + off);
    v4bf y;
    y[0] = (__bf16)(x[0] * sc); y[1] = (__bf16)(x[1] * sc);
    y[2] = (__bf16)(x[2] * sc); y[3] = (__bf16)(x[3] * sc);
    *(v4bf*)(out + idx) = y;
}

// ---------------------------------------------------------------------------
// K1: QKV projection. grid (64, 4, 3), block 256. Tile 128x128, BK=64.
// Register-prefetch pipeline; A fp32->bf16 cvt in staging regs; B bf16.
// z==0 bias scaled by QSCALE (matches pre-scaled Wq).
// ---------------------------------------------------------------------------
__global__ __launch_bounds__(256) void qkv_gemm(
    const float* __restrict__ xq, const float* __restrict__ xk, const float* __restrict__ xv,
    const __bf16* __restrict__ Wb,
    const float* __restrict__ bq, const float* __restrict__ bk, const float* __restrict__ bv,
    __bf16* __restrict__ Qo, __bf16* __restrict__ Ko, __bf16* __restrict__ VTo)
{
    const int z = blockIdx.z;
    const float*  x    = (z == 0) ? xq : (z == 1) ? xk : xv;
    const __bf16* W    = Wb + (size_t)z * 262144;
    const float*  bias = (z == 0) ? bq : (z == 1) ? bk : bv;
    const float   bsc  = (z == 0) ? QSCALE : 1.0f;

    const int tid = threadIdx.x, wave = tid >> 6, lane = tid & 63;
    const int quad = lane >> 4, r = lane & 15;
    const int wm = wave >> 1, wn = wave & 1;
    const int row0 = blockIdx.x * 128, col0 = blockIdx.y * 128;

    __shared__ __align__(16) __bf16 As[8192];
    __shared__ __align__(16) __bf16 Bs[8192];

    const float*  aptr[4];
    const __bf16* bptr[4];
    int adst[4], bdst[4];
    for (int j = 0; j < 4; j++) {
        const int e = tid + 256 * j;
        const int seg = e >> 6, ln = e & 63;
        aptr[j] = x + (size_t)(row0 + (seg >> 1) * 16 + (ln & 15)) * 512
                    + (seg & 1) * 32 + (ln >> 4) * 8;
        adst[j] = e * 8;
        const int segb = wave * 4 + j;
        bptr[j] = W + (size_t)(col0 + (segb >> 1) * 16 + r) * 512
                    + (segb & 1) * 32 + quad * 8;
        bdst[j] = (segb * 64 + lane) * 8;
    }

    v4f acc[4][4] = {};
    v8bf aReg[4], bReg[4];
    for (int j = 0; j < 4; j++) {
        aReg[j] = cvt8(aptr[j]);
        bReg[j] = *(const v8bf*)bptr[j];
    }

    for (int ki = 0; ki < 8; ki++) {
        __syncthreads();
        for (int j = 0; j < 4; j++) {
            *(v8bf*)&As[adst[j]] = aReg[j];
            *(v8bf*)&Bs[bdst[j]] = bReg[j];
        }
        __syncthreads();
        if (ki < 7) {
            const int kk = (ki + 1) * 64;
            for (int j = 0; j < 4; j++) {
                aReg[j] = cvt8(aptr[j] + kk);
                bReg[j] = *(const v8bf*)(bptr[j] + kk);
            }
        }
        for (int kc = 0; kc < 2; kc++) {
            v8bf a[4], b[4];
            for (int i = 0; i < 4; i++)
                a[i] = ((const v8bf*)As)[((wm * 4 + i) * 2 + kc) * 64 + lane];
            for (int i = 0; i < 4; i++)
                b[i] = ((const v8bf*)Bs)[((wn * 4 + i) * 2 + kc) * 64 + lane];
            for (int mi = 0; mi < 4; mi++)
                for (int ni = 0; ni < 4; ni++)
                    acc[mi][ni] = MFMA16(a[mi], b[ni], acc[mi][ni]);
        }
    }

    for (int ni = 0; ni < 4; ni++) {
        const int n = col0 + wn * 64 + ni * 16 + r;
        const float bv_ = bias[n] * bsc;
        const int hh = n >> 6, hd = n & 63;
        for (int mi = 0; mi < 4; mi++) {
            const int mbase = row0 + wm * 64 + mi * 16 + quad * 4;
            const int bb = mbase >> 11, s0 = mbase & 2047;
            if (z == 2) {
                v4bf pk;
                for (int i = 0; i < 4; i++)
                    pk[i] = (__bf16)(acc[mi][ni][i] + bv_);
                *(v4bf*)&VTo[((size_t)((bb * 8 + hh) * 64 + hd)) * 2048 + s0] = pk;
            } else {
                __bf16* dst = (z == 0) ? Qo : Ko;
                for (int i = 0; i < 4; i++)
                    dst[((size_t)((bb * 8 + hh) * 2048 + s0 + i)) * 64 + hd] =
                        (__bf16)(acc[mi][ni][i] + bv_);
            }
        }
    }
}

// ---------------------------------------------------------------------------
// K2: flash attention, streaming softmax (exp2, l via ones-MFMA).
// grid (32, 32), block 256. Register-prefetch K/V staging, 2 barriers/iter.
// ---------------------------------------------------------------------------
__global__ __launch_bounds__(256) void attn(
    const __bf16* __restrict__ Q, const __bf16* __restrict__ K,
    const __bf16* __restrict__ VT, const int* __restrict__ mask,
    __bf16* __restrict__ AO)
{
    const int bh = blockIdx.y, b = bh >> 3, h = bh & 7;
    const int tid = threadIdx.x, wave = tid >> 6, lane = tid & 63;
    const int quad = lane >> 4, r = lane & 15;
    const int q0 = blockIdx.x * 64 + wave * 16;

    const __bf16* Qb = Q  + (size_t)bh * 2048 * 64;
    const __bf16* Kb = K  + (size_t)bh * 2048 * 64;
    const __bf16* Vb = VT + (size_t)bh * 64 * 2048;
    const int*    mb = mask + (size_t)b * 2048;

    __shared__ __align__(16) __bf16 Kls[4096];        // 8 KB
    __shared__ __align__(16) __bf16 Vls[4096];        // 8 KB
    __shared__ __align__(16) __bf16 Pls[4][16][88];   // 11 KB (88-pad: fewer conflicts)
    __shared__ __bf16 biasLS[2048];                   // 4 KB: 0 or -1e10

    for (int i = tid; i < 2048; i += 256)
        biasLS[i] = (mb[i] != 0) ? (__bf16)0.f : (__bf16)(-1e10f);

    const int e1 = tid, e2 = tid + 256;
    int seg, l, t_, h_, rr, qd;
    seg = e1 >> 6; l = e1 & 63; t_ = seg >> 1; h_ = seg & 1; rr = l & 15; qd = l >> 4;
    const __bf16* kg1 = Kb + (size_t)(16 * t_ + rr) * 64   + h_ * 32 + qd * 8;
    const __bf16* vg1 = Vb + (size_t)(16 * t_ + rr) * 2048 + h_ * 32 + qd * 8;
    seg = e2 >> 6; l = e2 & 63; t_ = seg >> 1; h_ = seg & 1; rr = l & 15; qd = l >> 4;
    const __bf16* kg2 = Kb + (size_t)(16 * t_ + rr) * 64   + h_ * 32 + qd * 8;
    const __bf16* vg2 = Vb + (size_t)(16 * t_ + rr) * 2048 + h_ * 32 + qd * 8;

    v8bf qf0 = *(const v8bf*)(Qb + (size_t)(q0 + r) * 64 +      quad * 8);
    v8bf qf1 = *(const v8bf*)(Qb + (size_t)(q0 + r) * 64 + 32 + quad * 8);

    v8bf ones;
    for (int i = 0; i < 8; i++) ones[i] = (__bf16)1.0f;

    v4f o[4] = {};
    v4f lacc = {};           // row-sums of P via ones-MFMA; C-layout = o rows

    v8bf ks1 = *(const v8bf*)kg1, ks2 = *(const v8bf*)kg2;   // tile 0 -> regs
    v8bf vs1 = *(const v8bf*)vg1, vs2 = *(const v8bf*)vg2;

    for (int t = 0; t < 32; t++) {
        __syncthreads();                        // prev-tile readers done
        ((v8bf*)Kls)[e1] = ks1; ((v8bf*)Kls)[e2] = ks2;
        ((v8bf*)Vls)[e1] = vs1; ((v8bf*)Vls)[e2] = vs2;
        __syncthreads();                        // tile t visible
        if (t < 31) {                           // prefetch t+1 -> regs
            const int k0n = (t + 1) * 64;
            ks1 = *(const v8bf*)(kg1 + (size_t)k0n * 64);
            ks2 = *(const v8bf*)(kg2 + (size_t)k0n * 64);
            vs1 = *(const v8bf*)(vg1 + k0n);
            vs2 = *(const v8bf*)(vg2 + k0n);
        }
        const int k0 = t * 64;

        // ---- S^T = K.(Q*qscale)^T : lane holds keys {tt*16+quad*4+i}, query r
        v4f sa[4] = {};
        for (int tt = 0; tt < 4; tt++) {
            v8bf kf0 = ((const v8bf*)Kls)[(tt * 2 + 0) * 64 + lane];
            v8bf kf1 = ((const v8bf*)Kls)[(tt * 2 + 1) * 64 + lane];
            sa[tt] = MFMA16(kf0, qf0, sa[tt]);
            sa[tt] = MFMA16(kf1, qf1, sa[tt]);
        }

        // ---- p = 2^(s' + mb) : single v_exp_f32 per element (scale pre-folded)
        for (int tt = 0; tt < 4; tt++) {
            const v4bf bl = *(const v4bf*)&biasLS[k0 + tt * 16 + quad * 4];
            v4bf pk;
            for (int i = 0; i < 4; i++)
                pk[i] = (__bf16)exp2f(sa[tt][i] + (float)bl[i]);
            *(v4bf*)&Pls[wave][r][tt * 16 + quad * 4] = pk;
        }
        asm volatile("s_waitcnt lgkmcnt(0)" ::: "memory");  // same-wave cross-lane
        v8bf pa0 = *(const v8bf*)&Pls[wave][r][     quad * 8];
        v8bf pa1 = *(const v8bf*)&Pls[wave][r][32 + quad * 8];

        // ---- l += P @ 1 (row sums, lands aligned with o rows)
        lacc = MFMA16(pa0, ones, lacc);
        lacc = MFMA16(pa1, ones, lacc);

        // ---- O += P @ V
        for (int t2 = 0; t2 < 4; t2++) {
            v8bf vf0 = ((const v8bf*)Vls)[(t2 * 2 + 0) * 64 + lane];
            v8bf vf1 = ((const v8bf*)Vls)[(t2 * 2 + 1) * 64 + lane];
            o[t2] = MFMA16(pa0, vf0, o[t2]);
            o[t2] = MFMA16(pa1, vf1, o[t2]);
        }
    }

    // ---- epilogue: lacc[i] is l for row q0+quad*4+i (same rows as o[t2][i])
    for (int t2 = 0; t2 < 4; t2++) {
        const int hd = t2 * 16 + r;
        for (int i = 0; i < 4; i++) {
            const int s = q0 + quad * 4 + i;
            AO[((size_t)b * 2048 + s) * 512 + h * 64 + hd] = (__bf16)(o[t2][i] / lacc[i]);
        }
    }
}

// ---------------------------------------------------------------------------
// K3: output projection (unchanged). grid (64, 4), block 256.
// ---------------------------------------------------------------------------
__global__ __launch_bounds__(256) void out_gemm(
    const __bf16* __restrict__ Ai, const __bf16* __restrict__ W,
    const float* __restrict__ bias, float* __restrict__ y)
{
    const int tid = threadIdx.x, wave = tid >> 6, lane = tid & 63;
    const int quad = lane >> 4, r = lane & 15;
    const int wm = wave >> 1, wn = wave & 1;
    const int row0 = blockIdx.x * 128, col0 = blockIdx.y * 128;

    __shared__ __align__(16) __bf16 As[8192];
    __shared__ __align__(16) __bf16 Bs[8192];

    const __bf16* aptr[4];
    const __bf16* bptr[4];
    int dst_[4];
    for (int j = 0; j < 4; j++) {
        const int segb = wave * 4 + j;
        aptr[j] = Ai + (size_t)(row0 + (segb >> 1) * 16 + r) * 512 + (segb & 1) * 32 + quad * 8;
        bptr[j] = W  + (size_t)(col0 + (segb >> 1) * 16 + r) * 512 + (segb & 1) * 32 + quad * 8;
        dst_[j] = (segb * 64 + lane) * 8;
    }

    v4f acc[4][4] = {};
    v8bf aReg[4], bReg[4];
    for (int j = 0; j < 4; j++) {
        aReg[j] = *(const v8bf*)aptr[j];
        bReg[j] = *(const v8bf*)bptr[j];
    }

    for (int ki = 0; ki < 8; ki++) {
        __syncthreads();
        for (int j = 0; j < 4; j++) {
            *(v8bf*)&As[dst_[j]] = aReg[j];
            *(v8bf*)&Bs[dst_[j]] = bReg[j];
        }
        __syncthreads();
        if (ki < 7) {
            const int kk = (ki + 1) * 64;
            for (int j = 0; j < 4; j++) {
                aReg[j] = *(const v8bf*)(aptr[j] + kk);
                bReg[j] = *(const v8bf*)(bptr[j] + kk);
            }
        }
        for (int kc = 0; kc < 2; kc++) {
            v8bf a[4], b[4];
            for (int i = 0; i < 4; i++)
                a[i] = ((const v8bf*)As)[((wm * 4 + i) * 2 + kc) * 64 + lane];
            for (int i = 0; i < 4; i++)
                b[i] = ((const v8bf*)Bs)[((wn * 4 + i) * 2 + kc) * 64 + lane];
            for (int mi = 0; mi < 4; mi++)
                for (int ni = 0; ni < 4; ni++)
                    acc[mi][ni] = MFMA16(a[mi], b[ni], acc[mi][ni]);
        }
    }

    for (int ni = 0; ni < 4; ni++) {
        const int n = col0 + wn * 64 + ni * 16 + r;
        const float bv_ = bias[n];
        for (int mi = 0; mi < 4; mi++) {
            const int mbase = row0 + wm * 64 + mi * 16 + quad * 4;
            for (int i = 0; i < 4; i++)
                y[(size_t)(mbase + i) * 512 + n] = acc[mi][ni][i] + bv_;
        }
    }
}

// ---------------------------------------------------------------------------
extern "C" void kernel_launch(void* const* d_in, const int* in_sizes, int n_in,
                              void* d_out, int out_size, void* d_ws, size_t ws_size,
                              hipStream_t stream)
{
    const float* q    = (const float*)d_in[0];
    const float* k    = (const float*)d_in[1];
    const float* v    = (const float*)d_in[2];
    const int*   mask = (const int*)d_in[3];
    const float* Wq   = (const float*)d_in[4];
    const float* Wk   = (const float*)d_in[5];
    const float* Wv   = (const float*)d_in[6];
    const float* Wo   = (const float*)d_in[7];
    const float* bq   = (const float*)d_in[8];
    const float* bk   = (const float*)d_in[9];
    const float* bv   = (const float*)d_in[10];
    const float* bo   = (const float*)d_in[11];

    // ws (bf16 elems): Q[4M] K[4M] VT[4M] AO[4M] Wb[1M] -> 35.7 MB
    __bf16* ws  = (__bf16*)d_ws;
    __bf16* Qw  = ws;
    __bf16* Kw  = ws + 4194304;
    __bf16* VTw = ws + 8388608;
    __bf16* AOw = ws + 12582912;
    __bf16* Wb  = ws + 16777216;

    cvt_w<<<dim3(1024), 256, 0, stream>>>(Wq, Wk, Wv, Wo, Wb);
    qkv_gemm<<<dim3(64, 4, 3), 256, 0, stream>>>(q, k, v, Wb, bq, bk, bv, Qw, Kw, VTw);
    attn<<<dim3(32, 32), 256, 0, stream>>>(Qw, Kw, VTw, mask, AOw);
    out_gemm<<<dim3(64, 4), 256, 0, stream>>>(AOw, Wb + 786432, bo, (float*)d_out);
}

// Round 8
// 239.877 us; speedup vs baseline: 1.0023x; 1.0023x over previous
//
#include <hip/hip_runtime.h>
#include <hip/hip_bf16.h>

// MHA layer. B=4, S=2048, HID=512, H=8, HD=64. fp32 in/out, bf16 MFMA inside.
// R8: attn P-transpose ELIMINATED. The S^T C-layout fragments (lane(quad,r)
// holds P[q=r][key=tt*16+quad*4+i]) are exactly the B-operand of
// v_mfma_f32_16x16x16_bf16 (B'[n=lane&15][k=quad*4+j]). PV computed as
// O^T = VT x P^T with 16 K=16 MFMAs; no LDS round trip, no lgkm drain.
// Mask bias = C-init of the S^T MFMA (exp2 is a single v_exp). l = 16 scalar
// adds/iter + 2 end shuffles (per-lane scalar). Epilogue: packed v4bf stores.
// GEMMs unchanged from R7.

typedef __bf16 v8bf __attribute__((ext_vector_type(8)));
typedef __bf16 v4bf __attribute__((ext_vector_type(4)));
typedef float  v4f  __attribute__((ext_vector_type(4)));
typedef short  v4s  __attribute__((ext_vector_type(4)));

#define MFMA16(a, b, c) __builtin_amdgcn_mfma_f32_16x16x32_bf16((a), (b), (c), 0, 0, 0)

// K=16 MFMA for PV: A,B = 4 bf16 (2 VGPRs), C/D = 4 f32.
__device__ inline v4f MFMA_PV(v4bf a, v4bf b, v4f c) {
    return __builtin_amdgcn_mfma_f32_16x16x16bf16_1k(
        __builtin_bit_cast(v4s, a), __builtin_bit_cast(v4s, b), c, 0, 0, 0);
}

// 0.125 * log2(e): folded into Wq/bq so softmax uses exp2 directly.
#define QSCALE 0.1803368801111f

__device__ inline v8bf cvt8(const float* __restrict__ p) {
    const v4f f0 = *(const v4f*)p;
    const v4f f1 = *(const v4f*)(p + 4);
    v8bf r;
    r[0] = (__bf16)f0[0]; r[1] = (__bf16)f0[1]; r[2] = (__bf16)f0[2]; r[3] = (__bf16)f0[3];
    r[4] = (__bf16)f1[0]; r[5] = (__bf16)f1[1]; r[6] = (__bf16)f1[2]; r[7] = (__bf16)f1[3];
    return r;
}

// ---------------------------------------------------------------------------
// K0: convert Wq,Wk,Wv,Wo (each 512x512 fp32) -> bf16, concatenated.
// Wq additionally scaled by QSCALE (softmax exp2 folding).
// ---------------------------------------------------------------------------
__global__ __launch_bounds__(256) void cvt_w(
    const float* __restrict__ Wq, const float* __restrict__ Wk,
    const float* __restrict__ Wv, const float* __restrict__ Wo,
    __bf16* __restrict__ out)
{
    const int idx = (blockIdx.x * 256 + threadIdx.x) * 4;
    const int w = idx >> 18, off = idx & 262143;
    const float* src = (w == 0) ? Wq : (w == 1) ? Wk : (w == 2) ? Wv : Wo;
    const float sc = (w == 0) ? QSCALE : 1.0f;
    const v4f x = *(const v4f*)(src + off);
    v4bf y;
    y[0] = (__bf16)(x[0] * sc); y[1] = (__bf16)(x[1] * sc);
    y[2] = (__bf16)(x[2] * sc); y[3] = (__bf16)(x[3] * sc);
    *(v4bf*)(out + idx) = y;
}

// ---------------------------------------------------------------------------
// K1: QKV projection (unchanged from R7). grid (64, 4, 3), block 256.
// ---------------------------------------------------------------------------
__global__ __launch_bounds__(256) void qkv_gemm(
    const float* __restrict__ xq, const float* __restrict__ xk, const float* __restrict__ xv,
    const __bf16* __restrict__ Wb,
    const float* __restrict__ bq, const float* __restrict__ bk, const float* __restrict__ bv,
    __bf16* __restrict__ Qo, __bf16* __restrict__ Ko, __bf16* __restrict__ VTo)
{
    const int z = blockIdx.z;
    const float*  x    = (z == 0) ? xq : (z == 1) ? xk : xv;
    const __bf16* W    = Wb + (size_t)z * 262144;
    const float*  bias = (z == 0) ? bq : (z == 1) ? bk : bv;
    const float   bsc  = (z == 0) ? QSCALE : 1.0f;

    const int tid = threadIdx.x, wave = tid >> 6, lane = tid & 63;
    const int quad = lane >> 4, r = lane & 15;
    const int wm = wave >> 1, wn = wave & 1;
    const int row0 = blockIdx.x * 128, col0 = blockIdx.y * 128;

    __shared__ __align__(16) __bf16 As[8192];
    __shared__ __align__(16) __bf16 Bs[8192];

    const float*  aptr[4];
    const __bf16* bptr[4];
    int adst[4], bdst[4];
    for (int j = 0; j < 4; j++) {
        const int e = tid + 256 * j;
        const int seg = e >> 6, ln = e & 63;
        aptr[j] = x + (size_t)(row0 + (seg >> 1) * 16 + (ln & 15)) * 512
                    + (seg & 1) * 32 + (ln >> 4) * 8;
        adst[j] = e * 8;
        const int segb = wave * 4 + j;
        bptr[j] = W + (size_t)(col0 + (segb >> 1) * 16 + r) * 512
                    + (segb & 1) * 32 + quad * 8;
        bdst[j] = (segb * 64 + lane) * 8;
    }

    v4f acc[4][4] = {};
    v8bf aReg[4], bReg[4];
    for (int j = 0; j < 4; j++) {
        aReg[j] = cvt8(aptr[j]);
        bReg[j] = *(const v8bf*)bptr[j];
    }

    for (int ki = 0; ki < 8; ki++) {
        __syncthreads();
        for (int j = 0; j < 4; j++) {
            *(v8bf*)&As[adst[j]] = aReg[j];
            *(v8bf*)&Bs[bdst[j]] = bReg[j];
        }
        __syncthreads();
        if (ki < 7) {
            const int kk = (ki + 1) * 64;
            for (int j = 0; j < 4; j++) {
                aReg[j] = cvt8(aptr[j] + kk);
                bReg[j] = *(const v8bf*)(bptr[j] + kk);
            }
        }
        for (int kc = 0; kc < 2; kc++) {
            v8bf a[4], b[4];
            for (int i = 0; i < 4; i++)
                a[i] = ((const v8bf*)As)[((wm * 4 + i) * 2 + kc) * 64 + lane];
            for (int i = 0; i < 4; i++)
                b[i] = ((const v8bf*)Bs)[((wn * 4 + i) * 2 + kc) * 64 + lane];
            for (int mi = 0; mi < 4; mi++)
                for (int ni = 0; ni < 4; ni++)
                    acc[mi][ni] = MFMA16(a[mi], b[ni], acc[mi][ni]);
        }
    }

    for (int ni = 0; ni < 4; ni++) {
        const int n = col0 + wn * 64 + ni * 16 + r;
        const float bv_ = bias[n] * bsc;
        const int hh = n >> 6, hd = n & 63;
        for (int mi = 0; mi < 4; mi++) {
            const int mbase = row0 + wm * 64 + mi * 16 + quad * 4;
            const int bb = mbase >> 11, s0 = mbase & 2047;
            if (z == 2) {
                v4bf pk;
                for (int i = 0; i < 4; i++)
                    pk[i] = (__bf16)(acc[mi][ni][i] + bv_);
                *(v4bf*)&VTo[((size_t)((bb * 8 + hh) * 64 + hd)) * 2048 + s0] = pk;
            } else {
                __bf16* dst = (z == 0) ? Qo : Ko;
                for (int i = 0; i < 4; i++)
                    dst[((size_t)((bb * 8 + hh) * 2048 + s0 + i)) * 64 + hd] =
                        (__bf16)(acc[mi][ni][i] + bv_);
            }
        }
    }
}

// ---------------------------------------------------------------------------
// K2: flash attention, streaming softmax, transpose-free PV (O^T = VT x P^T).
// grid (32, 32), block 256 (4 waves x 16 queries). LDS ~25 KB.
// ---------------------------------------------------------------------------
__global__ __launch_bounds__(256) void attn(
    const __bf16* __restrict__ Q, const __bf16* __restrict__ K,
    const __bf16* __restrict__ VT, const int* __restrict__ mask,
    __bf16* __restrict__ AO)
{
    const int bh = blockIdx.y, b = bh >> 3, h = bh & 7;
    const int tid = threadIdx.x, wave = tid >> 6, lane = tid & 63;
    const int quad = lane >> 4, r = lane & 15;
    const int q0 = blockIdx.x * 64 + wave * 16;

    const __bf16* Qb = Q  + (size_t)bh * 2048 * 64;
    const __bf16* Kb = K  + (size_t)bh * 2048 * 64;
    const __bf16* Vb = VT + (size_t)bh * 64 * 2048;
    const int*    mb = mask + (size_t)b * 2048;

    __shared__ __align__(16) __bf16 Kls[4096];     // 8 KB, fragment-major
    __shared__ __align__(16) __bf16 Vls[64 * 72];  // 9 KB, row-major stride 72
    __shared__ float biasF[2048];                  // 8 KB: 0 or -1e10 per key

    for (int i = tid; i < 2048; i += 256)
        biasF[i] = (mb[i] != 0) ? 0.f : -1e10f;

    // --- K staging (fragment-major, entry e = 16B for lane e&63 of seg e>>6)
    const int e1 = tid, e2 = tid + 256;
    int seg, l_, t_, h_, rr, qd;
    seg = e1 >> 6; l_ = e1 & 63; t_ = seg >> 1; h_ = seg & 1; rr = l_ & 15; qd = l_ >> 4;
    const __bf16* kg1 = Kb + (size_t)(16 * t_ + rr) * 64 + h_ * 32 + qd * 8;
    seg = e2 >> 6; l_ = e2 & 63; t_ = seg >> 1; h_ = seg & 1; rr = l_ & 15; qd = l_ >> 4;
    const __bf16* kg2 = Kb + (size_t)(16 * t_ + rr) * 64 + h_ * 32 + qd * 8;

    // --- V staging (row-major): chunk c covers Vls[c>>3][(c&7)*8 .. +7]
    const int hd1 = tid >> 3, c1 = tid & 7;
    const __bf16* vg1 = Vb + (size_t)hd1 * 2048 + c1 * 8;
    const __bf16* vg2 = Vb + (size_t)(hd1 + 32) * 2048 + c1 * 8;
    const int dV1 = hd1 * 72 + c1 * 8, dV2 = (hd1 + 32) * 72 + c1 * 8;

    // Q fragments resident (pre-scaled by 0.125*log2e via cvt_w/qkv)
    v8bf qf0 = *(const v8bf*)(Qb + (size_t)(q0 + r) * 64 +      quad * 8);
    v8bf qf1 = *(const v8bf*)(Qb + (size_t)(q0 + r) * 64 + 32 + quad * 8);

    float ssum = 0.f;        // partial l for query q=r (this lane)
    v4f o[4] = {};           // O^T: lane holds hd=t2*16+quad*4+i, q=r

    v8bf ks1 = *(const v8bf*)kg1, ks2 = *(const v8bf*)kg2;   // tile 0 -> regs
    v8bf vs1 = *(const v8bf*)vg1, vs2 = *(const v8bf*)vg2;

    // per-lane Vls read base (elems): row = r (within hd-group), col = quad*4
    const int vbase = r * 72 + quad * 4;

    for (int t = 0; t < 32; t++) {
        __syncthreads();                        // prev-tile readers done
        ((v8bf*)Kls)[e1] = ks1; ((v8bf*)Kls)[e2] = ks2;
        *(v8bf*)&Vls[dV1] = vs1; *(v8bf*)&Vls[dV2] = vs2;
        __syncthreads();                        // tile t visible
        if (t < 31) {                           // prefetch t+1 -> regs
            const int k0n = (t + 1) * 64;
            ks1 = *(const v8bf*)(kg1 + (size_t)k0n * 64);
            ks2 = *(const v8bf*)(kg2 + (size_t)k0n * 64);
            vs1 = *(const v8bf*)(vg1 + k0n);
            vs2 = *(const v8bf*)(vg2 + k0n);
        }
        const int k0 = t * 64;

        // ---- S^T = K.Q^T with mask bias as C-init; keys tt*16+quad*4+i, q=r
        v4f sa[4];
        for (int tt = 0; tt < 4; tt++) {
            const v4f bias4 = *(const v4f*)&biasF[k0 + tt * 16 + quad * 4];
            v8bf kf0 = ((const v8bf*)Kls)[(tt * 2 + 0) * 64 + lane];
            v8bf kf1 = ((const v8bf*)Kls)[(tt * 2 + 1) * 64 + lane];
            sa[tt] = MFMA16(kf0, qf0, bias4);
            sa[tt] = MFMA16(kf1, qf1, sa[tt]);
        }

        // ---- p = 2^s (single v_exp; scale pre-folded, bias pre-added)
        v4bf pf[4];
        for (int tt = 0; tt < 4; tt++) {
            for (int i = 0; i < 4; i++) {
                const float p = exp2f(sa[tt][i]);
                ssum += p;
                pf[tt][i] = (__bf16)p;
            }
        }

        // ---- O^T += VT x P^T : pf[g] IS the K=16 B-fragment, no transpose.
        // A-fragment: VT[hd=t2*16+r][k0+g*16+quad*4 .. +3] from Vls.
        for (int g = 0; g < 4; g++)
            for (int t2 = 0; t2 < 4; t2++) {
                const v4bf vf = *(const v4bf*)&Vls[t2 * 1152 + vbase + g * 16];
                o[t2] = MFMA_PV(vf, pf[g], o[t2]);
            }
    }

    // ---- l for q=r: reduce the 4 partials (lanes quad 0..3, same r)
    ssum += __shfl_xor(ssum, 16);
    ssum += __shfl_xor(ssum, 32);
    const float inv = 1.0f / ssum;

    // ---- store: row s=q0+r, cols h*64 + t2*16 + quad*4 .. +3 (packed v4bf)
    __bf16* dst = AO + ((size_t)b * 2048 + q0 + r) * 512 + h * 64 + quad * 4;
    for (int t2 = 0; t2 < 4; t2++) {
        v4bf pk;
        for (int i = 0; i < 4; i++)
            pk[i] = (__bf16)(o[t2][i] * inv);
        *(v4bf*)(dst + t2 * 16) = pk;
    }
}

// ---------------------------------------------------------------------------
// K3: output projection (unchanged from R7). grid (64, 4), block 256.
// ---------------------------------------------------------------------------
__global__ __launch_bounds__(256) void out_gemm(
    const __bf16* __restrict__ Ai, const __bf16* __restrict__ W,
    const float* __restrict__ bias, float* __restrict__ y)
{
    const int tid = threadIdx.x, wave = tid >> 6, lane = tid & 63;
    const int quad = lane >> 4, r = lane & 15;
    const int wm = wave >> 1, wn = wave & 1;
    const int row0 = blockIdx.x * 128, col0 = blockIdx.y * 128;

    __shared__ __align__(16) __bf16 As[8192];
    __shared__ __align__(16) __bf16 Bs[8192];

    const __bf16* aptr[4];
    const __bf16* bptr[4];
    int dst_[4];
    for (int j = 0; j < 4; j++) {
        const int segb = wave * 4 + j;
        aptr[j] = Ai + (size_t)(row0 + (segb >> 1) * 16 + r) * 512 + (segb & 1) * 32 + quad * 8;
        bptr[j] = W  + (size_t)(col0 + (segb >> 1) * 16 + r) * 512 + (segb & 1) * 32 + quad * 8;
        dst_[j] = (segb * 64 + lane) * 8;
    }

    v4f acc[4][4] = {};
    v8bf aReg[4], bReg[4];
    for (int j = 0; j < 4; j++) {
        aReg[j] = *(const v8bf*)aptr[j];
        bReg[j] = *(const v8bf*)bptr[j];
    }

    for (int ki = 0; ki < 8; ki++) {
        __syncthreads();
        for (int j = 0; j < 4; j++) {
            *(v8bf*)&As[dst_[j]] = aReg[j];
            *(v8bf*)&Bs[dst_[j]] = bReg[j];
        }
        __syncthreads();
        if (ki < 7) {
            const int kk = (ki + 1) * 64;
            for (int j = 0; j < 4; j++) {
                aReg[j] = *(const v8bf*)(aptr[j] + kk);
                bReg[j] = *(const v8bf*)(bptr[j] + kk);
            }
        }
        for (int kc = 0; kc < 2; kc++) {
            v8bf a[4], b[4];
            for (int i = 0; i < 4; i++)
                a[i] = ((const v8bf*)As)[((wm * 4 + i) * 2 + kc) * 64 + lane];
            for (int i = 0; i < 4; i++)
                b[i] = ((const v8bf*)Bs)[((wn * 4 + i) * 2 + kc) * 64 + lane];
            for (int mi = 0; mi < 4; mi++)
                for (int ni = 0; ni < 4; ni++)
                    acc[mi][ni] = MFMA16(a[mi], b[ni], acc[mi][ni]);
        }
    }

    for (int ni = 0; ni < 4; ni++) {
        const int n = col0 + wn * 64 + ni * 16 + r;
        const float bv_ = bias[n];
        for (int mi = 0; mi < 4; mi++) {
            const int mbase = row0 + wm * 64 + mi * 16 + quad * 4;
            for (int i = 0; i < 4; i++)
                y[(size_t)(mbase + i) * 512 + n] = acc[mi][ni][i] + bv_;
        }
    }
}

// ---------------------------------------------------------------------------
extern "C" void kernel_launch(void* const* d_in, const int* in_sizes, int n_in,
                              void* d_out, int out_size, void* d_ws, size_t ws_size,
                              hipStream_t stream)
{
    const float* q    = (const float*)d_in[0];
    const float* k    = (const float*)d_in[1];
    const float* v    = (const float*)d_in[2];
    const int*   mask = (const int*)d_in[3];
    const float* Wq   = (const float*)d_in[4];
    const float* Wk   = (const float*)d_in[5];
    const float* Wv   = (const float*)d_in[6];
    const float* Wo   = (const float*)d_in[7];
    const float* bq   = (const float*)d_in[8];
    const float* bk   = (const float*)d_in[9];
    const float* bv   = (const float*)d_in[10];
    const float* bo   = (const float*)d_in[11];

    // ws (bf16 elems): Q[4M] K[4M] VT[4M] AO[4M] Wb[1M] -> 35.7 MB
    __bf16* ws  = (__bf16*)d_ws;
    __bf16* Qw  = ws;
    __bf16* Kw  = ws + 4194304;
    __bf16* VTw = ws + 8388608;
    __bf16* AOw = ws + 12582912;
    __bf16* Wb  = ws + 16777216;

    cvt_w<<<dim3(1024), 256, 0, stream>>>(Wq, Wk, Wv, Wo, Wb);
    qkv_gemm<<<dim3(64, 4, 3), 256, 0, stream>>>(q, k, v, Wb, bq, bk, bv, Qw, Kw, VTw);
    attn<<<dim3(32, 32), 256, 0, stream>>>(Qw, Kw, VTw, mask, AOw);
    out_gemm<<<dim3(64, 4), 256, 0, stream>>>(AOw, Wb + 786432, bo, (float*)d_out);
}